// Round 6
// baseline (145.288 us; speedup 1.0000x reference)
//
#include <hip/hip_runtime.h>
#include <math.h>

#define BB 64
#define LL 512
#define DD 512
#define CC 50
#define NC 100
#define NCP 112
#define WST 520     // LDS row stride (bf16 units): bank step 4 -> 2-way max

// ws byte layout:
//   0: loss f32   4: cnt f32   8: done counter (int)
//   64:      scomb f32 [64][112]                   (28672 B)
//   28736:   span partials bf16 [8 seg][64 b][512] (524288 B)
//   553024:  Wtop bf16 [112][512] (rows 100..111 = poison, excluded in epilogue)
//   667712:  Wbot bf16 [112][512]
//   782400:  tvb bf16 [32768][512]  (33554432 B) — bf16 copy of text_vec
#define WSB_LOSS  0
#define WSB_CNT   4
#define WSB_DONE  8
#define WSB_SCOMB 64
#define WSB_PART  28736
#define WSB_WTOP  553024
#define WSB_WBOT  667712
#define WSB_TVB   782400

typedef __attribute__((ext_vector_type(8))) short bf16x8;
typedef __attribute__((ext_vector_type(4))) float f32x4;

static __device__ __forceinline__ unsigned short f2bf(float x) {
    unsigned int u = __float_as_uint(x);
    u += 0x7FFFu + ((u >> 16) & 1u);          // RNE
    return (unsigned short)(u >> 16);
}
static __device__ __forceinline__ float bf2f(unsigned short h) {
    return __uint_as_float(((unsigned int)h) << 16);
}

// ---------------------------------------------------------------------------
// k_prep: blocks [0,512): block=(b<<3)|seg handles 64 rows. Streams the rows
//   once: f32 read -> bf16 copy to tvb, plus span-masked partial sums ->
//   bf16 partial[seg][b][512] (zeros if segment empty).
// blocks [512,528): W transpose/convert -> Wtop/Wbot bf16.
// block 512 zeroes loss/cnt/done.
// ---------------------------------------------------------------------------
__global__ __launch_bounds__(256) void k_prep(
    const float* __restrict__ tv, const int* __restrict__ sbj_bound,
    const float* __restrict__ Wst, const float* __restrict__ Wen,
    char* __restrict__ wsb)
{
    __shared__ float sh[128 * 53];
    const int t = threadIdx.x;
    const int blk = blockIdx.x;

    if (blk < 512) {
        const int b = blk >> 3, seg = blk & 7;
        const int start = sbj_bound[2 * b], end = sbj_bound[2 * b + 1];
        const int c4 = t & 127, par = t >> 7;
        const size_t rowbase = (size_t)b * LL + seg * 64;
        const float* bp = tv + rowbase * DD + c4 * 4;
        unsigned short* tvb = (unsigned short*)(wsb + WSB_TVB);
        unsigned short* op = tvb + rowbase * DD + c4 * 4;
        float4 acc = {0, 0, 0, 0};
#pragma unroll 4
        for (int i = 0; i < 32; i++) {
            const int r = par + 2 * i;
            float4 v = *(const float4*)(bp + (size_t)r * DD);
            ushort4 o;
            o.x = f2bf(v.x); o.y = f2bf(v.y); o.z = f2bf(v.z); o.w = f2bf(v.w);
            *(ushort4*)(op + (size_t)r * DD) = o;
            const int gr = seg * 64 + r;
            if (gr >= start && gr <= end) {
                acc.x += v.x; acc.y += v.y; acc.z += v.z; acc.w += v.w;
            }
        }
        float4* buf = (float4*)sh;
        buf[t] = acc;
        __syncthreads();
        if (t < 128) {
            float4 x = buf[t], y = buf[t + 128];
            unsigned short* part = (unsigned short*)(wsb + WSB_PART);
            ushort4 o;
            o.x = f2bf(x.x + y.x); o.y = f2bf(x.y + y.y);
            o.z = f2bf(x.z + y.z); o.w = f2bf(x.w + y.w);
            *(ushort4*)(part + ((size_t)(seg * BB + b)) * DD + t * 4) = o;
        }
    } else {
        const int bi = blk - 512;              // 0..15
        const int mat = bi >> 3;               // 0: W_start, 1: W_end
        const int cj = bi & 7;                 // 128-row k-chunk of [0,1024)
        const float* W = mat ? Wen : Wst;
        const int kbase = cj * 128;
        const float* src = W + (size_t)kbase * CC;
#pragma unroll
        for (int i = 0; i < 25; i++) {
            int idx = t + i * 256;             // [0,6400)
            int kr = idx / 50, c = idx - kr * 50;
            sh[kr * 53 + c] = src[idx];
        }
        __syncthreads();
        unsigned short* outp =
            (unsigned short*)(wsb + ((cj < 4) ? WSB_WTOP : WSB_WBOT));
        const int kout = kbase & 511;
#pragma unroll
        for (int i = 0; i < 25; i++) {
            int idx = t + i * 256;             // 50 n x 128 k
            int n = idx >> 7, kl = idx & 127;
            outp[((size_t)(mat * CC + n)) * DD + kout + kl] = f2bf(sh[kl * 53 + n]);
        }
        if (bi == 0 && t == 0) {
            *(float*)(wsb + WSB_LOSS) = 0.0f;
            *(float*)(wsb + WSB_CNT)  = 0.0f;
            *(int*)(wsb + WSB_DONE)   = 0;
        }
    }
}

// ---------------------------------------------------------------------------
// k_scomb: 4 blocks x 16 batches. Combine 8 seg-partials -> sbj bf16 LDS
// (div by span count), then per-wave column strips of sbj @ Wbot^T -> scomb.
// ---------------------------------------------------------------------------
__global__ __launch_bounds__(256) void k_scomb(
    const int* __restrict__ sbj_bound,
    const float* __restrict__ bst, const float* __restrict__ ben,
    char* __restrict__ wsb)
{
    __shared__ __align__(16) unsigned short sbjb[16 * WST];
    const int t = threadIdx.x;
    const int g = blockIdx.x;
    const unsigned short* part = (const unsigned short*)(wsb + WSB_PART);

#pragma unroll
    for (int i = 0; i < 8; i++) {
        int idx = t + i * 256;                 // [0, 2048)
        int bo = idx >> 7, d4 = idx & 127;
        int b = g * 16 + bo;
        float inv = 1.0f / (float)(sbj_bound[2 * b + 1] - sbj_bound[2 * b] + 1);
        float sx = 0.f, sy = 0.f, sz = 0.f, sw = 0.f;
#pragma unroll
        for (int seg = 0; seg < 8; seg++) {
            ushort4 v = *(const ushort4*)(part + ((size_t)(seg * BB + b)) * DD + d4 * 4);
            sx += bf2f(v.x); sy += bf2f(v.y); sz += bf2f(v.z); sw += bf2f(v.w);
        }
        ushort4 o;
        o.x = f2bf(sx * inv); o.y = f2bf(sy * inv);
        o.z = f2bf(sz * inv); o.w = f2bf(sw * inv);
        *(ushort4*)(sbjb + bo * WST + d4 * 4) = o;
    }
    __syncthreads();

    const int wv = t >> 6, ln = t & 63, tc = ln & 15, quad = ln >> 4;
    const unsigned short* wbot = (const unsigned short*)(wsb + WSB_WBOT);
    float* scomb = (float*)(wsb + WSB_SCOMB);
    const unsigned short* Af = sbjb + tc * WST + quad * 8;
    const int nu = (wv < 3) ? 2 : 1;
    for (int j = 0; j < nu; j++) {
        const int u = wv * 2 + j;
        f32x4 acc = (f32x4)(0.0f);
        const unsigned short* Bf = wbot + (size_t)(u * 16 + tc) * DD + quad * 8;
#pragma unroll
        for (int kk = 0; kk < DD; kk += 32) {
            bf16x8 af = *(const bf16x8*)(Af + kk);
            bf16x8 bf = *(const bf16x8*)(Bf + kk);
            acc = __builtin_amdgcn_mfma_f32_16x16x32_bf16(af, bf, acc, 0, 0, 0);
        }
        const int cc = u * 16 + tc;
        const float bias = (cc < CC) ? bst[cc] : ((cc < NC) ? ben[cc - CC] : 0.0f);
#pragma unroll
        for (int i = 0; i < 4; i++) {
            int b = g * 16 + quad * 4 + i;
            scomb[b * NCP + cc] = acc[i] + bias;
        }
    }
}

// ---------------------------------------------------------------------------
// k_main: 256 blocks x 512 thr. B staged once into padded LDS; A fragments
// loaded DIRECT global->VGPR as bf16 (L3-hot tvb, no conversion, 16 dwordx4
// in flight per lane); one barrier; MFMA burst; fused CE epilogue.
// ---------------------------------------------------------------------------
__global__ __launch_bounds__(512, 2) void k_main(
    const int* __restrict__ mask,
    const int* __restrict__ obj_s, const int* __restrict__ obj_e,
    char* __restrict__ wsb, float* __restrict__ out)
{
    __shared__ __align__(16) unsigned short Wt[NCP * WST];   // 116480 B
    __shared__ float red[16];
    const int t = threadIdx.x, wv = t >> 6, ln = t & 63;
    const int tc = ln & 15, quad = ln >> 4;
    const int m0w = blockIdx.x * 128 + wv * 16;
    const int b = blockIdx.x >> 2;
    const unsigned short* wtop = (const unsigned short*)(wsb + WSB_WTOP);
    const unsigned short* tvb  = (const unsigned short*)(wsb + WSB_TVB);

    // B global loads into regs first (their waits won't drain A behind them)
    bf16x8 breg[14];
#pragma unroll
    for (int i = 0; i < 14; i++) {
        int idx = t + i * 512;
        int n = idx >> 6, ch = idx & 63;
        breg[i] = *(const bf16x8*)(wtop + (size_t)n * DD + ch * 8);
    }
    // A preload: all 16 K-fragments for this lane's row, direct bf16
    const unsigned short* Abase = tvb + (size_t)(m0w + tc) * DD + quad * 8;
    bf16x8 af[16];
#pragma unroll
    for (int j = 0; j < 16; j++) af[j] = *(const bf16x8*)(Abase + j * 32);

    // commit B to LDS (waits only B's vmcnt; A stays in flight)
#pragma unroll
    for (int i = 0; i < 14; i++) {
        int idx = t + i * 512;
        int n = idx >> 6, ch = idx & 63;
        *(bf16x8*)(Wt + n * WST + ch * 8) = breg[i];
    }
    __syncthreads();

    f32x4 acc[7];
#pragma unroll
    for (int u = 0; u < 7; u++) acc[u] = (f32x4)(0.0f);
    const unsigned short* Wf = Wt + tc * WST + quad * 8;

#pragma unroll
    for (int j = 0; j < 16; j++) {
#pragma unroll
        for (int u = 0; u < 7; u++) {
            bf16x8 bf = *(const bf16x8*)(Wf + u * 16 * WST + j * 32);
            acc[u] = __builtin_amdgcn_mfma_f32_16x16x32_bf16(af[j], bf, acc[u], 0, 0, 0);
        }
    }

    // ---- fused CE epilogue (C/D: col=lane&15, row=quad*4+reg) ----
    const float* scomb = (const float*)(wsb + WSB_SCOMB);
    float sc[7];
#pragma unroll
    for (int u = 0; u < 7; u++) sc[u] = scomb[b * NCP + u * 16 + tc];

    float loss_local = 0.0f, cnt_local = 0.0f;
#pragma unroll
    for (int i = 0; i < 4; i++) {
        const int l = (m0w + quad * 4 + i) & (LL - 1);
        const int lab1 = obj_s[b * LL + l];
        const int lab2 = obj_e[b * LL + l] + CC;
        const int mk   = mask[b * LL + l];
        float lg[7];
#pragma unroll
        for (int u = 0; u < 7; u++) lg[u] = acc[u][i] + sc[u];
        float m1 = fmaxf(fmaxf(lg[0], lg[1]), lg[2]);
        if (tc < 2) m1 = fmaxf(m1, lg[3]);
        float m2 = fmaxf(lg[4], lg[5]);
        if (tc >= 2) m2 = fmaxf(m2, lg[3]);
        if (tc < 4)  m2 = fmaxf(m2, lg[6]);
#pragma unroll
        for (int off = 1; off < 16; off <<= 1) {
            m1 = fmaxf(m1, __shfl_xor(m1, off, 16));
            m2 = fmaxf(m2, __shfl_xor(m2, off, 16));
        }
        float e1 = expf(lg[0] - m1) + expf(lg[1] - m1) + expf(lg[2] - m1)
                 + ((tc < 2) ? expf(lg[3] - m1) : 0.0f);
        float e2 = expf(lg[4] - m2) + expf(lg[5] - m2)
                 + ((tc >= 2) ? expf(lg[3] - m2) : 0.0f)
                 + ((tc < 4)  ? expf(lg[6] - m2) : 0.0f);
        float t1 = 0.0f, t2 = 0.0f;
#pragma unroll
        for (int u = 0; u < 7; u++) {
            const int cc = u * 16 + tc;
            if (cc == lab1) t1 = lg[u];
            if (cc == lab2) t2 = lg[u];
        }
#pragma unroll
        for (int off = 1; off < 16; off <<= 1) {
            e1 += __shfl_xor(e1, off, 16);
            e2 += __shfl_xor(e2, off, 16);
            t1 += __shfl_xor(t1, off, 16);
            t2 += __shfl_xor(t2, off, 16);
        }
        if (tc == 0) {
            const float nll = (m1 + logf(e1) - t1) + (m2 + logf(e2) - t2);
            loss_local += mk ? nll : 0.0f;
            cnt_local  += mk ? 1.0f : 0.0f;
        }
    }
#pragma unroll
    for (int off = 1; off < 64; off <<= 1) {
        loss_local += __shfl_xor(loss_local, off);
        cnt_local  += __shfl_xor(cnt_local, off);
    }
    if (ln == 0) { red[wv * 2] = loss_local; red[wv * 2 + 1] = cnt_local; }
    __syncthreads();
    if (t == 0) {
        float Ls = 0.f, Cs = 0.f;
#pragma unroll
        for (int w = 0; w < 8; w++) { Ls += red[w * 2]; Cs += red[w * 2 + 1]; }
        float* wsf = (float*)wsb;
        atomicAdd(&wsf[0], Ls);
        atomicAdd(&wsf[1], Cs);
        __threadfence();
        int old = atomicAdd((int*)(wsb + WSB_DONE), 1);
        if (old == (int)gridDim.x - 1) {
            float L = atomicAdd(&wsf[0], 0.0f);   // coherent read
            float C = atomicAdd(&wsf[1], 0.0f);
            out[0] = L / C;
        }
    }
}

extern "C" void kernel_launch(void* const* d_in, const int* in_sizes, int n_in,
                              void* d_out, int out_size, void* d_ws, size_t ws_size,
                              hipStream_t stream) {
    const float* tv   = (const float*)d_in[0];
    const int*   mask = (const int*)d_in[1];
    const int*   sbj  = (const int*)d_in[2];
    const int*   objs = (const int*)d_in[3];
    const int*   obje = (const int*)d_in[4];
    const float* Wst  = (const float*)d_in[5];
    const float* bst  = (const float*)d_in[6];
    const float* Wen  = (const float*)d_in[7];
    const float* ben  = (const float*)d_in[8];
    float* out = (float*)d_out;
    char*  wsb = (char*)d_ws;

    k_prep<<<528, 256, 0, stream>>>(tv, sbj, Wst, Wen, wsb);
    k_scomb<<<4, 256, 0, stream>>>(sbj, bst, ben, wsb);
    k_main<<<256, 512, 0, stream>>>(mask, objs, obje, wsb, out);
}